// Round 11
// baseline (224.863 us; speedup 1.0000x reference)
//
#include <hip/hip_runtime.h>
#include <math.h>

// Problem constants
#define B_   64
#define S_   64
#define W_   12
#define V_   32000
#define SYM_ 128
#define HID_ 256
#define E_   64
#define R_   32

// ---------------------------------------------------------------------------
// K1: embedding sums for story (rows 0..4095) and query (rows 4096..4159)
// ---------------------------------------------------------------------------
__global__ __launch_bounds__(128) void k_embed(
    const int* __restrict__ story, const int* __restrict__ query,
    const float* __restrict__ we, const float* __restrict__ pe,
    float* __restrict__ X) {
  int row = blockIdx.x;
  int e = threadIdx.x;
  const int* idx = (row < 4096) ? story + row * W_ : query + (row - 4096) * W_;
  float acc = 0.f;
#pragma unroll
  for (int w = 0; w < W_; ++w)
    acc = fmaf(we[(long)idx[w] * SYM_ + e], pe[w * SYM_ + e], acc);
  X[row * SYM_ + e] = acc;
}

// ---------------------------------------------------------------------------
// K2 v8: 16-row tiles -> 1300 blocks (~5 blocks/CU, 2x TLP of v7).
// Block = (16-row tile, head); 256 thr (4 waves); wave wv owns rows 4wv..4wv+3.
// Layer 1: lane l -> cols 4l..4l+3; W1 streamed direct from global (dense
// 1KB/wave); X tile in LDS [row][136], broadcast b128 reads; no k-loop
// barriers. Layer 2 E: lane = col, 4 rows. Layer 2 R: lanes split rows
// (h2 = l>>5 -> rows 4wv+2h2..+1, col l&31) -> no wasted lanes.
// ---------------------------------------------------------------------------
__global__ __launch_bounds__(256) void k_mlp(
    const float* __restrict__ X,
    const float* __restrict__ ueW1, const float* __restrict__ ueb1,
    const float* __restrict__ ueW2, const float* __restrict__ ueb2,
    const float* __restrict__ urW1, const float* __restrict__ urb1,
    const float* __restrict__ urW2, const float* __restrict__ urb2,
    const float* __restrict__ ieW1, const float* __restrict__ ieb1,
    const float* __restrict__ ieW2, const float* __restrict__ ieb2,
    const float* __restrict__ irW1, const float* __restrict__ irb1,
    const float* __restrict__ irW2, const float* __restrict__ irb2,
    float* __restrict__ oE0, float* __restrict__ oE1,
    float* __restrict__ oR0, float* __restrict__ oR1, float* __restrict__ oR2) {
  // phase 1: XT [16 row][136] = 2176 floats. phase 2: HT [16 row][260] = 4160.
  __shared__ float SM[4160];

  int h = blockIdx.x % 5;
  int tile = blockIdx.x / 5;
  int rowbase = tile * 16;
  bool isQ = (rowbase >= 4096);
  bool isE = (h < 2);
  const float* W1 = isE ? (isQ ? ieW1 : ueW1) + h * (SYM_ * HID_)
                        : (isQ ? irW1 : urW1) + (h - 2) * (SYM_ * HID_);
  const float* b1 = isE ? (isQ ? ieb1 : ueb1) + h * HID_
                        : (isQ ? irb1 : urb1) + (h - 2) * HID_;
  const float* W2 = isE ? (isQ ? ieW2 : ueW2) + h * (HID_ * E_)
                        : (isQ ? irW2 : urW2) + (h - 2) * (HID_ * R_);
  const float* b2 = isE ? (isQ ? ieb2 : ueb2) + h * E_
                        : (isQ ? irb2 : urb2) + (h - 2) * R_;
  float* out = (h == 0) ? oE0 : (h == 1) ? oE1 : (h == 2) ? oR0 : (h == 3) ? oR1 : oR2;

  int tid = threadIdx.x;
  int wv = tid >> 6;    // wave: rows 4wv..4wv+3
  int l = tid & 63;     // lane: cols 4l..4l+3 (layer 1)

  // stage X tile, natural layout [row][k], stride 136 (512 float4s)
#pragma unroll
  for (int c = 0; c < 2; ++c) {
    int i = tid + 256 * c;
    int row = i >> 5, k4 = (i & 31) * 4;
    *(float4*)&SM[row * 136 + k4] = *(const float4*)(X + (long)(rowbase + row) * SYM_ + k4);
  }
  __syncthreads();

  float a[4][4];
#pragma unroll
  for (int i = 0; i < 4; ++i)
#pragma unroll
    for (int q = 0; q < 4; ++q) a[i][q] = 0.f;

  const float* W1p = W1 + 4 * l;
#pragma unroll 2
  for (int kg = 0; kg < 32; ++kg) {
    float4 w0 = *(const float4*)(W1p + (long)(4 * kg + 0) * HID_);
    float4 w1 = *(const float4*)(W1p + (long)(4 * kg + 1) * HID_);
    float4 w2 = *(const float4*)(W1p + (long)(4 * kg + 2) * HID_);
    float4 w3 = *(const float4*)(W1p + (long)(4 * kg + 3) * HID_);
    float4 xr[4];
#pragma unroll
    for (int i = 0; i < 4; ++i)
      xr[i] = *(const float4*)&SM[(4 * wv + i) * 136 + 4 * kg];  // broadcast b128
#pragma unroll
    for (int i = 0; i < 4; ++i) {
      a[i][0] = fmaf(xr[i].x, w0.x, a[i][0]);
      a[i][1] = fmaf(xr[i].x, w0.y, a[i][1]);
      a[i][2] = fmaf(xr[i].x, w0.z, a[i][2]);
      a[i][3] = fmaf(xr[i].x, w0.w, a[i][3]);
      a[i][0] = fmaf(xr[i].y, w1.x, a[i][0]);
      a[i][1] = fmaf(xr[i].y, w1.y, a[i][1]);
      a[i][2] = fmaf(xr[i].y, w1.z, a[i][2]);
      a[i][3] = fmaf(xr[i].y, w1.w, a[i][3]);
      a[i][0] = fmaf(xr[i].z, w2.x, a[i][0]);
      a[i][1] = fmaf(xr[i].z, w2.y, a[i][1]);
      a[i][2] = fmaf(xr[i].z, w2.z, a[i][2]);
      a[i][3] = fmaf(xr[i].z, w2.w, a[i][3]);
      a[i][0] = fmaf(xr[i].w, w3.x, a[i][0]);
      a[i][1] = fmaf(xr[i].w, w3.y, a[i][1]);
      a[i][2] = fmaf(xr[i].w, w3.z, a[i][2]);
      a[i][3] = fmaf(xr[i].w, w3.w, a[i][3]);
    }
  }
  __syncthreads();  // XT dead; HT overlays
  // bias + tanh -> HT[row][c] stride 260, dense b128 writes
  {
    float4 b1v = *(const float4*)(b1 + 4 * l);
#pragma unroll
    for (int i = 0; i < 4; ++i) {
      float4 hv = make_float4(tanhf(a[i][0] + b1v.x), tanhf(a[i][1] + b1v.y),
                              tanhf(a[i][2] + b1v.z), tanhf(a[i][3] + b1v.w));
      *(float4*)&SM[(4 * wv + i) * 260 + 4 * l] = hv;
    }
  }
  __syncthreads();
  // layer 2
  if (isE) {
    // lane = out col l, rows 4wv..4wv+3
    float acc[4] = {};
#pragma unroll 2
    for (int c4 = 0; c4 < 64; ++c4) {
      float w0 = W2[(long)(4 * c4 + 0) * E_ + l];
      float w1 = W2[(long)(4 * c4 + 1) * E_ + l];
      float w2 = W2[(long)(4 * c4 + 2) * E_ + l];
      float w3 = W2[(long)(4 * c4 + 3) * E_ + l];
#pragma unroll
      for (int i = 0; i < 4; ++i) {
        float4 hh = *(const float4*)&SM[(4 * wv + i) * 260 + 4 * c4];  // bcast
        acc[i] = fmaf(hh.x, w0, fmaf(hh.y, w1, fmaf(hh.z, w2, fmaf(hh.w, w3, acc[i]))));
      }
    }
    float bb = b2[l];
#pragma unroll
    for (int i = 0; i < 4; ++i)
      out[(long)(rowbase + 4 * wv + i) * E_ + l] = acc[i] + bb;
  } else {
    // lanes split rows: h2 = l>>5 -> rows 4wv+2h2, 4wv+2h2+1; col lc = l&31
    int h2 = l >> 5, lc = l & 31;
    int rA = 4 * wv + 2 * h2;
    float acc[2] = {};
#pragma unroll 2
    for (int c4 = 0; c4 < 64; ++c4) {
      float w0 = W2[(long)(4 * c4 + 0) * R_ + lc];
      float w1 = W2[(long)(4 * c4 + 1) * R_ + lc];
      float w2 = W2[(long)(4 * c4 + 2) * R_ + lc];
      float w3 = W2[(long)(4 * c4 + 3) * R_ + lc];
#pragma unroll
      for (int i = 0; i < 2; ++i) {
        float4 hh = *(const float4*)&SM[(rA + i) * 260 + 4 * c4];  // 2-addr bcast
        acc[i] = fmaf(hh.x, w0, fmaf(hh.y, w1, fmaf(hh.z, w2, fmaf(hh.w, w3, acc[i]))));
      }
    }
    float bb = b2[lc];
#pragma unroll
    for (int i = 0; i < 2; ++i)
      out[(long)(rowbase + rA + i) * R_ + lc] = acc[i] + bb;
  }
}

// ---------------------------------------------------------------------------
// K_gram v2: writes TRANSPOSED Wt[b][m][j][s]  (unchanged)
// ---------------------------------------------------------------------------
__global__ __launch_bounds__(256) void k_gram(
    const float* __restrict__ e1, const float* __restrict__ e2,
    const float* __restrict__ r1, const float* __restrict__ r2,
    const float* __restrict__ r3, float* __restrict__ Wt) {
  int b = blockIdx.x / 9, m = blockIdx.x % 9;
  const float* sE = ((m < 6) ? e1 : e2) + (long)b * S_ * E_;
  const float* jE = ((m == 2 || m == 5 || m == 8) ? e2 : e1) + (long)b * S_ * E_;
  int sk = m / 3, jk = m % 3;
  const float* sR = ((sk == 0) ? r1 : (sk == 1) ? r2 : r3) + (long)b * S_ * R_;
  const float* jR = ((jk == 0) ? r1 : (jk == 1) ? r2 : r3) + (long)b * S_ * R_;

  __shared__ float Es[64][68], Ej[64][68], Rs[64][36], Rj[64][36];
  int tid = threadIdx.x;
  for (int i = tid; i < 1024; i += 256) {
    int row = i >> 4, c = i & 15;
    *(float4*)&Es[row][4 * c] = *(const float4*)(sE + row * 64 + 4 * c);
    *(float4*)&Ej[row][4 * c] = *(const float4*)(jE + row * 64 + 4 * c);
  }
  for (int i = tid; i < 512; i += 256) {
    int row = i >> 3, c = i & 7;
    *(float4*)&Rs[row][4 * c] = *(const float4*)(sR + row * 32 + 4 * c);
    *(float4*)&Rj[row][4 * c] = *(const float4*)(jR + row * 32 + 4 * c);
  }
  __syncthreads();

  int s0 = (tid & 15) * 4, j0 = (tid >> 4) * 4;
  float ed[4][4] = {}, rd[4][4] = {};  // [s][j]
#pragma unroll 4
  for (int k = 0; k < 16; ++k) {
    float4 es[4], ej[4];
#pragma unroll
    for (int i = 0; i < 4; ++i) {
      es[i] = *(const float4*)&Es[s0 + i][4 * k];
      ej[i] = *(const float4*)&Ej[j0 + i][4 * k];
    }
#pragma unroll
    for (int i = 0; i < 4; ++i)
#pragma unroll
      for (int j = 0; j < 4; ++j)
        ed[i][j] = fmaf(es[i].x, ej[j].x, fmaf(es[i].y, ej[j].y,
                   fmaf(es[i].z, ej[j].z, fmaf(es[i].w, ej[j].w, ed[i][j]))));
  }
#pragma unroll 4
  for (int k = 0; k < 8; ++k) {
    float4 rs[4], rj[4];
#pragma unroll
    for (int i = 0; i < 4; ++i) {
      rs[i] = *(const float4*)&Rs[s0 + i][4 * k];
      rj[i] = *(const float4*)&Rj[j0 + i][4 * k];
    }
#pragma unroll
    for (int i = 0; i < 4; ++i)
#pragma unroll
      for (int j = 0; j < 4; ++j)
        rd[i][j] = fmaf(rs[i].x, rj[j].x, fmaf(rs[i].y, rj[j].y,
                   fmaf(rs[i].z, rj[j].z, fmaf(rs[i].w, rj[j].w, rd[i][j]))));
  }
  float* wout = Wt + (long)(b * 9 + m) * 4096;
#pragma unroll
  for (int jj = 0; jj < 4; ++jj) {
    float4 o4 = make_float4(ed[0][jj] * rd[0][jj], ed[1][jj] * rd[1][jj],
                            ed[2][jj] * rd[2][jj], ed[3][jj] * rd[3][jj]);
    *(float4*)(wout + (j0 + jj) * 64 + s0) = o4;  // [j][s]
  }
}

// ---------------------------------------------------------------------------
// K_scan v6 (unchanged): outer-product recurrence, LDS-staged Wt.
// ---------------------------------------------------------------------------
__global__ __launch_bounds__(256) void k_scan(
    const float* __restrict__ e1g, const float* __restrict__ e2g,
    const float* __restrict__ Wt, float4* __restrict__ acd) {
  __shared__ float WtL[9 * 512];
  int b = blockIdx.x & 63;
  int g = blockIdx.x >> 6;
  int tid = threadIdx.x;
  int wv = tid >> 6;
  int lane = tid & 63;             // = s
  int f0 = g * 8 + wv * 2;
  int f1 = f0 + 1;
  const float* Wb = Wt + (long)b * 9 * 4096;
  long eoff = ((long)b * 64 + lane) * 64;
  float e1x = e1g[eoff + f0], e1y = e1g[eoff + f1];
  float e2x = e2g[eoff + f0], e2y = e2g[eoff + f1];

  float pW0 = 0.f, pM0 = 0.f, pB0 = 0.f;
  float pW1 = 0.f, pM1 = 0.f, pB1 = 0.f;
  float ca0 = e2x, cc0 = 0.f, cd0 = e1x;
  float ca1 = e2y, cc1 = 0.f, cd1 = e1y;
  float ka0 = 0.f, kc0 = 0.f, kd0 = 0.f;
  float ka1 = 0.f, kc1 = 0.f, kd1 = 0.f;

  for (int jc = 0; jc < 8; ++jc) {
    __syncthreads();
    for (int i = tid; i < 1152; i += 256) {
      int m = i >> 7;
      int off = (i & 127) * 4;
      *(float4*)&WtL[m * 512 + off] = *(const float4*)(Wb + m * 4096 + jc * 512 + off);
    }
    __syncthreads();
#pragma unroll
    for (int jj = 0; jj < 8; ++jj) {
      int j = jc * 8 + jj;
      float wa = WtL[0 * 512 + jj * 64 + lane];
      float wc = WtL[1 * 512 + jj * 64 + lane];
      float wd = WtL[2 * 512 + jj * 64 + lane];
      float ma = WtL[3 * 512 + jj * 64 + lane];
      float mc = WtL[4 * 512 + jj * 64 + lane];
      float md = WtL[5 * 512 + jj * 64 + lane];
      float ba = WtL[6 * 512 + jj * 64 + lane];
      float bc = WtL[7 * 512 + jj * 64 + lane];
      float bd = WtL[8 * 512 + jj * 64 + lane];
      float aj0 = __int_as_float(__builtin_amdgcn_readlane(__float_as_int(ca0), j));
      float cj0 = __int_as_float(__builtin_amdgcn_readlane(__float_as_int(cc0), j));
      float dj0 = __int_as_float(__builtin_amdgcn_readlane(__float_as_int(cd0), j));
      float aj1 = __int_as_float(__builtin_amdgcn_readlane(__float_as_int(ca1), j));
      float cj1 = __int_as_float(__builtin_amdgcn_readlane(__float_as_int(cc1), j));
      float dj1 = __int_as_float(__builtin_amdgcn_readlane(__float_as_int(cd1), j));
      bool own = (lane == j);
      ka0 = own ? ca0 : ka0; kc0 = own ? cc0 : kc0; kd0 = own ? cd0 : kd0;
      ka1 = own ? ca1 : ka1; kc1 = own ? cc1 : kc1; kd1 = own ? cd1 : kd1;
      pW0 = fmaf(wa, aj0, pW0); pW0 = fmaf(wc, cj0, pW0); pW0 = fmaf(wd, dj0, pW0);
      pM0 = fmaf(ma, aj0, pM0); pM0 = fmaf(mc, cj0, pM0); pM0 = fmaf(md, dj0, pM0);
      pB0 = fmaf(ba, aj0, pB0); pB0 = fmaf(bc, cj0, pB0); pB0 = fmaf(bd, dj0, pB0);
      pW1 = fmaf(wa, aj1, pW1); pW1 = fmaf(wc, cj1, pW1); pW1 = fmaf(wd, dj1, pW1);
      pM1 = fmaf(ma, aj1, pM1); pM1 = fmaf(mc, cj1, pM1); pM1 = fmaf(md, dj1, pM1);
      pB1 = fmaf(ba, aj1, pB1); pB1 = fmaf(bc, cj1, pB1); pB1 = fmaf(bd, dj1, pB1);
      ca0 = e2x - pW0; cc0 = pW0 - pM0; cd0 = e1x - pB0;
      ca1 = e2y - pW1; cc1 = pW1 - pM1; cd1 = e1y - pB1;
    }
  }
  acd[eoff + f0] = make_float4(ka0, kc0, kd0, 0.f);
  acd[eoff + f1] = make_float4(ka1, kc1, kd1, 0.f);
}

// ---------------------------------------------------------------------------
// K_infer (unchanged)
// ---------------------------------------------------------------------------
__global__ __launch_bounds__(1024) void k_infer(
    const float4* __restrict__ acd,
    const float* __restrict__ e1, const float* __restrict__ e2,
    const float* __restrict__ r1, const float* __restrict__ r2,
    const float* __restrict__ r3,
    const float* __restrict__ qe1, const float* __restrict__ qr1,
    const float* __restrict__ qr2, const float* __restrict__ qr3,
    const float* __restrict__ lng, const float* __restrict__ lnb,
    float* __restrict__ isum) {
  int b = blockIdx.x, tid = threadIdx.x;
  __shared__ float hista[64 * 65], histc[64 * 65], histd[64 * 65];
  __shared__ float vlds[9 * 64];
  __shared__ float ivec[64];
  __shared__ float u1s[64], u2s[64];
  __shared__ float dsc[64];

  {
    const float4* ab = acd + (long)b * 4096;
    for (int idx = tid; idx < 4096; idx += 1024) {
      float4 hv = ab[idx];
      int j = idx >> 6, f = idx & 63;
      hista[j * 65 + f] = hv.x;
      histc[j * 65 + f] = hv.y;
      histd[j * 65 + f] = hv.z;
    }
  }
  if (tid < 576) {
    int pk = tid >> 6, j = tid & 63;
    int p = pk / 3, k = pk % 3;
    const float* rv = ((k == 0) ? r1 : (k == 1) ? r2 : r3) + ((long)b * 64 + j) * 32;
    const float* q = ((p == 0) ? qr1 : (p == 1) ? qr2 : qr3) + b * 32;
    float acc = 0.f;
#pragma unroll
    for (int t = 0; t < 8; ++t) {
      float4 rv4 = *(const float4*)(rv + 4 * t);
      float4 q4 = *(const float4*)(q + 4 * t);
      acc = fmaf(rv4.x, q4.x, fmaf(rv4.y, q4.y,
            fmaf(rv4.z, q4.z, fmaf(rv4.w, q4.w, acc))));
    }
    vlds[pk * 64 + j] = acc;
  }
  if (tid < 64) ivec[tid] = qe1[b * 64 + tid];
  __syncthreads();

  int f = tid >> 4, jsl = tid & 15;
  int dotd = tid >> 3, dt = tid & 7;
  int which = dotd >> 6, dj = dotd & 63;
  const float* erow = (which ? e2 : e1) + ((long)b * 64 + dj) * 64 + dt * 8;
  float isacc = 0.f;
  for (int p = 0; p < 3; ++p) {
    {
      float acc = 0.f;
#pragma unroll
      for (int t = 0; t < 8; ++t)
        acc = fmaf(erow[t], ivec[dt * 8 + t], acc);
      acc += __shfl_xor(acc, 1, 64);
      acc += __shfl_xor(acc, 2, 64);
      acc += __shfl_xor(acc, 4, 64);
      if (dt == 0) { if (which) u2s[dj] = acc; else u1s[dj] = acc; }
    }
    __syncthreads();
    float part = 0.f;
#pragma unroll
    for (int i = 0; i < 4; ++i) {
      int j = jsl * 4 + i;
      float ca = u1s[j] * vlds[(p * 3 + 0) * 64 + j];
      float cc = u1s[j] * vlds[(p * 3 + 1) * 64 + j];
      float cd = u2s[j] * vlds[(p * 3 + 2) * 64 + j];
      part = fmaf(ca, hista[j * 65 + f],
             fmaf(cc, histc[j * 65 + f],
             fmaf(cd, histd[j * 65 + f], part)));
    }
    part += __shfl_xor(part, 1, 64);
    part += __shfl_xor(part, 2, 64);
    part += __shfl_xor(part, 4, 64);
    part += __shfl_xor(part, 8, 64);
    if (jsl == 0) dsc[f] = part;
    __syncthreads();
    if (tid < 64) {
      float v = dsc[tid];
      float mu = v;
#pragma unroll
      for (int mm = 1; mm <= 32; mm <<= 1) mu += __shfl_xor(mu, mm, 64);
      mu *= (1.f / 64.f);
      float d = v - mu;
      float vr = d * d;
#pragma unroll
      for (int mm = 1; mm <= 32; mm <<= 1) vr += __shfl_xor(vr, mm, 64);
      vr *= (1.f / 64.f);
      float iv = d * (1.f / sqrtf(vr + 1e-5f)) * lng[p * 64 + tid] + lnb[p * 64 + tid];
      ivec[tid] = iv;
      isacc += iv;
    }
    __syncthreads();
  }
  if (tid < 64) isum[b * 64 + tid] = isacc;
}

// ---------------------------------------------------------------------------
// K5: out[b,v] = sum_e isum[b,e] * Z[e,v]   (unchanged)
// ---------------------------------------------------------------------------
__global__ __launch_bounds__(256) void k_final(
    const float* __restrict__ isum, const float* __restrict__ Zm,
    float* __restrict__ out) {
  __shared__ float isT[64 * 68];
  int tid = threadIdx.x;
  for (int i = tid; i < 4096; i += 256) {
    int bb = i >> 6, e = i & 63;
    isT[e * 68 + bb] = isum[i];
  }
  __syncthreads();
  int tr = tid >> 4, tc = tid & 15;
  int v0 = blockIdx.x * 64 + tc * 4;
  float acc[4][4] = {};
#pragma unroll 2
  for (int e = 0; e < 64; ++e) {
    float4 a4 = *(const float4*)&isT[e * 68 + 4 * tr];
    float4 z4 = *(const float4*)(Zm + (long)e * V_ + v0);
    float as[4] = {a4.x, a4.y, a4.z, a4.w};
    float zs[4] = {z4.x, z4.y, z4.z, z4.w};
#pragma unroll
    for (int i = 0; i < 4; ++i)
#pragma unroll
      for (int j = 0; j < 4; ++j) acc[i][j] = fmaf(as[i], zs[j], acc[i][j]);
  }
#pragma unroll
  for (int i = 0; i < 4; ++i) {
    float4 o4 = make_float4(acc[i][0], acc[i][1], acc[i][2], acc[i][3]);
    *(float4*)(out + (long)(4 * tr + i) * V_ + v0) = o4;
  }
}

// ---------------------------------------------------------------------------
extern "C" void kernel_launch(void* const* d_in, const int* in_sizes, int n_in,
                              void* d_out, int out_size, void* d_ws, size_t ws_size,
                              hipStream_t stream) {
  const int* story = (const int*)d_in[0];
  const int* query = (const int*)d_in[1];
  const float* we = (const float*)d_in[2];
  const float* pe = (const float*)d_in[3];
  const float* ueW1 = (const float*)d_in[4];
  const float* ueb1 = (const float*)d_in[5];
  const float* ueW2 = (const float*)d_in[6];
  const float* ueb2 = (const float*)d_in[7];
  const float* urW1 = (const float*)d_in[8];
  const float* urb1 = (const float*)d_in[9];
  const float* urW2 = (const float*)d_in[10];
  const float* urb2 = (const float*)d_in[11];
  const float* ieW1 = (const float*)d_in[12];
  const float* ieb1 = (const float*)d_in[13];
  const float* ieW2 = (const float*)d_in[14];
  const float* ieb2 = (const float*)d_in[15];
  const float* irW1 = (const float*)d_in[16];
  const float* irb1 = (const float*)d_in[17];
  const float* irW2 = (const float*)d_in[18];
  const float* irb2 = (const float*)d_in[19];
  const float* lng = (const float*)d_in[20];
  const float* lnb = (const float*)d_in[21];
  const float* Zm = (const float*)d_in[22];

  float* ws = (float*)d_ws;
  float* X = ws;                        // 4160*128 = 532480
  float* e1 = X + 532480;               // 4160*64  = 266240
  float* e2 = e1 + 266240;              // 266240
  float* r1 = e2 + 266240;              // 4160*32  = 133120
  float* r2 = r1 + 133120;              // 133120
  float* r3 = r2 + 133120;              // 133120
  float* isum = r3 + 133120;            // 4096
  float* Wt = isum + 4096;              // 9*64*4096 = 2359296
  float4* acd = (float4*)(Wt + 2359296);  // 64*64*64 float4 = 4 MB
  float* qe1 = e1 + 4096 * 64;
  float* qr1 = r1 + 4096 * 32;
  float* qr2 = r2 + 4096 * 32;
  float* qr3 = r3 + 4096 * 32;
  float* outF = (float*)d_out;

  k_embed<<<4160, 128, 0, stream>>>(story, query, we, pe, X);
  k_mlp<<<260 * 5, 256, 0, stream>>>(X, ueW1, ueb1, ueW2, ueb2,
                                     urW1, urb1, urW2, urb2,
                                     ieW1, ieb1, ieW2, ieb2,
                                     irW1, irb1, irW2, irb2,
                                     e1, e2, r1, r2, r3);
  k_gram<<<64 * 9, 256, 0, stream>>>(e1, e2, r1, r2, r3, Wt);
  k_scan<<<512, 256, 0, stream>>>(e1, e2, Wt, acd);
  k_infer<<<B_, 1024, 0, stream>>>(acd, e1, e2, r1, r2, r3, qe1, qr1, qr2, qr3,
                                   lng, lnb, isum);
  k_final<<<V_ / 64, 256, 0, stream>>>(isum, Zm, outF);
}